// Round 3
// baseline (195.092 us; speedup 1.0000x reference)
//
#include <hip/hip_runtime.h>

// DoReFa dense: out = q_in(3-bit) @ (sign(W)*E) + b,  E = mean|W|
//   out[i,j] = (E/7) * sum_k r[i,k]*sign(W[k,j]),  r in 0..7 -- exact in i8 MFMA.
// R3: m201-faithful 8-phase schedule (per-phase ds_read/stage/MFMA interleave,
//     counted vmcnt(2) once per K-tile). T1+T2+T5 retained from R2.

static constexpr int BATCH  = 8192;
static constexpr int IN_CH  = 4096;
static constexpr int NUNITS = 4096;
static constexpr int TPB    = 256;

typedef int v4i __attribute__((ext_vector_type(4)));

// ---- workspace layout ----
static constexpr size_t A8_OFF   = 0;
static constexpr size_t A8_BYTES = (size_t)BATCH * IN_CH;    // 32 MB
static constexpr size_t BT_OFF   = A8_OFF + A8_BYTES;
static constexpr size_t BT_BYTES = (size_t)NUNITS * IN_CH;   // 16 MB
static constexpr int    NPART    = 4096;
static constexpr size_t PART_OFF = BT_OFF + BT_BYTES;
static constexpr size_t SCALE_OFF= PART_OFF + NPART * sizeof(float);

// ------------------------------------------------------------- scale finalize
__global__ __launch_bounds__(TPB) void k_scale(const float* __restrict__ partials,
                                               float* __restrict__ scale) {
    __shared__ float red[TPB];
    float s = 0.f;
    for (int i = threadIdx.x; i < NPART; i += TPB) s += partials[i];
    red[threadIdx.x] = s;
    __syncthreads();
    for (int off = TPB / 2; off > 0; off >>= 1) {
        if ((int)threadIdx.x < off) red[threadIdx.x] += red[threadIdx.x + off];
        __syncthreads();
    }
    if (threadIdx.x == 0) {
        float E = red[0] / (float)((size_t)IN_CH * NUNITS);
        *scale = E / 7.0f;
    }
}

// ------------------------------------------------------------- quantize A
__device__ __forceinline__ unsigned int q4(float4 v) {
    unsigned int b0 = (unsigned int)(int)rintf(fminf(1.0f, fabsf(v.x)) * 7.0f);
    unsigned int b1 = (unsigned int)(int)rintf(fminf(1.0f, fabsf(v.y)) * 7.0f);
    unsigned int b2 = (unsigned int)(int)rintf(fminf(1.0f, fabsf(v.z)) * 7.0f);
    unsigned int b3 = (unsigned int)(int)rintf(fminf(1.0f, fabsf(v.w)) * 7.0f);
    return b0 | (b1 << 8) | (b2 << 16) | (b3 << 24);
}

__global__ __launch_bounds__(TPB) void k_quant_a(const float4* __restrict__ x4,
                                                 uint4* __restrict__ a16) {
    const size_t t = (size_t)blockIdx.x * TPB + threadIdx.x;
    uint4 o;
    o.x = q4(x4[t * 4 + 0]);
    o.y = q4(x4[t * 4 + 1]);
    o.z = q4(x4[t * 4 + 2]);
    o.w = q4(x4[t * 4 + 3]);
    a16[t] = o;
}

// -------------------------- sign(W) transpose to [N][K]  +  fused |W| partial sum
__global__ __launch_bounds__(TPB) void k_signT(const float* __restrict__ W,
                                               char* __restrict__ bt,
                                               float* __restrict__ partials) {
    __shared__ char tile[64][68];
    __shared__ float red[TPB];
    const int bk = blockIdx.x & 63;
    const int bn = blockIdx.x >> 6;
    const int t  = threadIdx.x;
    const int c  = t & 63;
    const int r0 = t >> 6;
    float asum = 0.f;
#pragma unroll
    for (int i = 0; i < 16; ++i) {
        int r = i * 4 + r0;
        float w = W[(size_t)(bk * 64 + r) * NUNITS + bn * 64 + c];
        asum += fabsf(w);
        tile[c][r] = (w > 0.f) ? 1 : ((w < 0.f) ? -1 : 0);
    }
    __syncthreads();
    const int n  = t >> 2;
    const int kk = (t & 3) * 16;
    char o[16];
#pragma unroll
    for (int j = 0; j < 16; ++j) o[j] = tile[n][kk + j];
    *(uint4*)(bt + (size_t)(bn * 64 + n) * IN_CH + bk * 64 + kk) = *(const uint4*)o;

    red[t] = asum;
    __syncthreads();
    for (int off = TPB / 2; off > 0; off >>= 1) {
        if (t < off) red[t] += red[t + off];
        __syncthreads();
    }
    if (t == 0) partials[blockIdx.x] = red[0];
}

// ---------------------------------------------------------------- GEMM
// 256x256 tile, K-tile = 128 B, 8 waves (2Mx4N), mfma_i32_16x16x64_i8.
// 8 phases per 2 K-tiles; each phase: {ds_reads, stage chunk, barrier,
// lgkm(0), setprio(1), 16 MFMA, setprio(0), barrier}; vmcnt(2) at p3/p7.
__device__ __forceinline__ void gload_lds16(const void* g, void* l) {
    __builtin_amdgcn_global_load_lds((const __attribute__((address_space(1))) void*)g,
                                     (__attribute__((address_space(3))) void*)l,
                                     16, 0, 0);
}

#define VMCNT2   asm volatile("s_waitcnt vmcnt(2)" ::: "memory")
#define VMCNT0   asm volatile("s_waitcnt vmcnt(0)" ::: "memory")
#define LGKM0    asm volatile("s_waitcnt lgkmcnt(0)" ::: "memory")
#define SCHEDB   __builtin_amdgcn_sched_barrier(0)
#define BARRIER  __builtin_amdgcn_s_barrier()
#define PRIO1    __builtin_amdgcn_s_setprio(1)
#define PRIO0    __builtin_amdgcn_s_setprio(0)

static constexpr int NT = IN_CH / 128;   // 32 K-tiles

__global__ __launch_bounds__(512, 2) void k_gemm(const char* __restrict__ A8,
                                                 const char* __restrict__ BT,
                                                 const float* __restrict__ scale_p,
                                                 const float* __restrict__ bias,
                                                 float* __restrict__ out) {
    __shared__ char As[2][32768];   // [256 rows][128 B], XOR-swizzled
    __shared__ char Bs[2][32768];

    const int t    = threadIdx.x;
    const int bid  = blockIdx.x;                  // 512 blocks
    const int swzb = (bid & 7) * 64 + (bid >> 3); // XCD swizzle (bijective)
    const int bRow = swzb >> 4;
    const int bCol = swzb & 15;
    const int lane = t & 63;
    const int wid  = t >> 6;
    const int wm   = wid >> 2;                    // 0..1
    const int wn   = wid & 3;                     // 0..3
    const int lr   = lane & 15;
    const int lk4  = lane >> 4;

    const size_t aBase = (size_t)(bRow * 256) * IN_CH;
    const size_t bBase = (size_t)(bCol * 256) * IN_CH;

    // swizzled read cols: byte col = s*64 + lk4*16, XOR ((row&7)<<4); row&7 == lr&7
    const int ceff0 = (lk4 * 16) ^ ((lr & 7) << 4);
    const int ceff1 = ceff0 ^ 64;

    // staging: issue q covers rows q*64 + (t>>3), col (t&7)*16 (inverse-swizzled source)
    const int srow  = t >> 3;
    const int scol  = ((t & 7) * 16) ^ ((srow & 7) << 4);
    const int sldso = t * 16;

    v4i acc[8][4] = {};
    v4i a0[4][2], a1[4][2], b01[2][2], b23[2][2];

#define STAGE(kt, q)                                                                  \
    do {                                                                              \
        const int _b = (kt) & 1;                                                      \
        if ((q) < 4)                                                                  \
            gload_lds16(A8 + aBase + (size_t)((q) * 64 + srow) * IN_CH + (kt) * 128 + scol, \
                        &As[_b][(q & 3) * 8192 + sldso]);                             \
        else                                                                          \
            gload_lds16(BT + bBase + (size_t)(((q) - 4) * 64 + srow) * IN_CH + (kt) * 128 + scol, \
                        &Bs[_b][((q) - 4) * 8192 + sldso]);                           \
    } while (0)

#define READ_A0(Ab)                                                    \
    _Pragma("unroll") for (int m = 0; m < 4; ++m) {                    \
        const int ra = (wm * 128 + m * 16 + lr) * 128;                 \
        a0[m][0] = *(const v4i*)((Ab) + ra + ceff0);                   \
        a0[m][1] = *(const v4i*)((Ab) + ra + ceff1);                   \
    }
#define READ_A1(Ab)                                                    \
    _Pragma("unroll") for (int m = 0; m < 4; ++m) {                    \
        const int ra = (wm * 128 + (m + 4) * 16 + lr) * 128;           \
        a1[m][0] = *(const v4i*)((Ab) + ra + ceff0);                   \
        a1[m][1] = *(const v4i*)((Ab) + ra + ceff1);                   \
    }
#define READ_B01(Bb)                                                   \
    _Pragma("unroll") for (int n = 0; n < 2; ++n) {                    \
        const int rb = (wn * 64 + n * 16 + lr) * 128;                  \
        b01[n][0] = *(const v4i*)((Bb) + rb + ceff0);                  \
        b01[n][1] = *(const v4i*)((Bb) + rb + ceff1);                  \
    }
#define READ_B23(Bb)                                                   \
    _Pragma("unroll") for (int n = 0; n < 2; ++n) {                    \
        const int rb = (wn * 64 + (n + 2) * 16 + lr) * 128;            \
        b23[n][0] = *(const v4i*)((Bb) + rb + ceff0);                  \
        b23[n][1] = *(const v4i*)((Bb) + rb + ceff1);                  \
    }
#define MFMA16(arr, brr, mo, no)                                                       \
    PRIO1;                                                                             \
    _Pragma("unroll") for (int m = 0; m < 4; ++m)                                      \
        _Pragma("unroll") for (int n = 0; n < 2; ++n)                                  \
            _Pragma("unroll") for (int s = 0; s < 2; ++s)                              \
                acc[(mo) + m][(no) + n] = __builtin_amdgcn_mfma_i32_16x16x64_i8(       \
                    arr[m][s], brr[n][s], acc[(mo) + m][(no) + n], 0, 0, 0);           \
    PRIO0

    // ---- prologue: tile0 full (8) + tile1 chunk0 (2); drain tile0 ----
#pragma unroll
    for (int q = 0; q < 8; ++q) STAGE(0, q);
    STAGE(1, 0); STAGE(1, 1);
    VMCNT2; SCHEDB;
    BARRIER;

    for (int T = 0; T < NT; T += 2) {
        const char* Ab0 = As[0]; const char* Bb0 = Bs[0];
        const char* Ab1 = As[1]; const char* Bb1 = Bs[1];
        const bool more = (T + 2 < NT);

        // ---- p0: tile T (buf0)
        READ_A0(Ab0); READ_B01(Bb0);
        STAGE(T + 1, 2); STAGE(T + 1, 3);
        SCHEDB; BARRIER; LGKM0; SCHEDB;
        MFMA16(a0, b01, 0, 0); SCHEDB; BARRIER;

        // ---- p1
        READ_B23(Bb0);
        STAGE(T + 1, 4); STAGE(T + 1, 5);
        SCHEDB; BARRIER; LGKM0; SCHEDB;
        MFMA16(a0, b23, 0, 2); SCHEDB; BARRIER;

        // ---- p2
        READ_A1(Ab0);
        STAGE(T + 1, 6); STAGE(T + 1, 7);
        SCHEDB; BARRIER; LGKM0; SCHEDB;
        MFMA16(a1, b01, 4, 0); SCHEDB; BARRIER;

        // ---- p3: vmcnt covers tile T+1 for p4's reads
        if (more) { STAGE(T + 2, 0); STAGE(T + 2, 1); VMCNT2; }
        else      { VMCNT0; }
        SCHEDB; BARRIER; SCHEDB;
        MFMA16(a1, b23, 4, 2); SCHEDB; BARRIER;

        // ---- p4: tile T+1 (buf1)
        READ_A0(Ab1); READ_B01(Bb1);
        if (more) { STAGE(T + 2, 2); STAGE(T + 2, 3); }
        SCHEDB; BARRIER; LGKM0; SCHEDB;
        MFMA16(a0, b01, 0, 0); SCHEDB; BARRIER;

        // ---- p5
        READ_B23(Bb1);
        if (more) { STAGE(T + 2, 4); STAGE(T + 2, 5); }
        SCHEDB; BARRIER; LGKM0; SCHEDB;
        MFMA16(a0, b23, 0, 2); SCHEDB; BARRIER;

        // ---- p6
        READ_A1(Ab1);
        if (more) { STAGE(T + 2, 6); STAGE(T + 2, 7); }
        SCHEDB; BARRIER; LGKM0; SCHEDB;
        MFMA16(a1, b01, 4, 0); SCHEDB; BARRIER;

        // ---- p7: vmcnt covers tile T+2 for next-iteration p0 reads
        if (more) { STAGE(T + 3, 0); STAGE(T + 3, 1); VMCNT2; }
        SCHEDB; BARRIER; SCHEDB;
        MFMA16(a1, b23, 4, 2); SCHEDB; BARRIER;
    }

    // ---- epilogue
    const float scale = *scale_p;
    const int orow0 = bRow * 256 + wm * 128;
    const int ocol0 = bCol * 256 + wn * 64;
#pragma unroll
    for (int m = 0; m < 8; ++m) {
#pragma unroll
        for (int n = 0; n < 4; ++n) {
            const int col = ocol0 + n * 16 + lr;
            const float bb = bias[col];
            const int rbase = orow0 + m * 16 + lk4 * 4;
#pragma unroll
            for (int j = 0; j < 4; ++j)
                out[(size_t)(rbase + j) * NUNITS + col] = scale * (float)acc[m][n][j] + bb;
        }
    }
#undef STAGE
#undef READ_A0
#undef READ_A1
#undef READ_B01
#undef READ_B23
#undef MFMA16
}

// ---------------------------------------------------------------- launch
extern "C" void kernel_launch(void* const* d_in, const int* in_sizes, int n_in,
                              void* d_out, int out_size, void* d_ws, size_t ws_size,
                              hipStream_t stream) {
    const float* x  = (const float*)d_in[0];
    const float* W  = (const float*)d_in[1];
    const float* b  = (const float*)d_in[2];
    float* out      = (float*)d_out;

    char*  ws       = (char*)d_ws;
    char*  A8       = ws + A8_OFF;
    char*  BT       = ws + BT_OFF;
    float* partials = (float*)(ws + PART_OFF);
    float* scale    = (float*)(ws + SCALE_OFF);

    k_signT<<<(IN_CH / 64) * (NUNITS / 64), TPB, 0, stream>>>(W, BT, partials);
    k_scale<<<1, TPB, 0, stream>>>(partials, scale);
    k_quant_a<<<(BATCH * (IN_CH / 16)) / TPB, TPB, 0, stream>>>((const float4*)x, (uint4*)A8);
    k_gemm<<<(BATCH / 256) * (NUNITS / 256), 512, 0, stream>>>(A8, BT, scale, b, out);
}

// Round 4
// 181.875 us; speedup vs baseline: 1.0727x; 1.0727x over previous
//
#include <hip/hip_runtime.h>

// DoReFa dense: out = q_in(3-bit) @ (sign(W)*E) + b,  E = mean|W|
//   out[i,j] = (E/7) * sum_k r[i,k]*sign(W[k,j]),  r in 0..7 -- exact in i8 MFMA.
// R4: 3-buffer BK=64 GEMM, ONE barrier per K-tile, wave-drift overlap.
//     LDS row = A-row 64B || B-row 64B (128B), 3-bit XOR slot swizzle (free reads).
//     Stage 2 tiles ahead into the retired buffer; counted vmcnt(4); setprio MFMA.

static constexpr int BATCH  = 8192;
static constexpr int IN_CH  = 4096;
static constexpr int NUNITS = 4096;
static constexpr int TPB    = 256;

typedef int v4i __attribute__((ext_vector_type(4)));

// ---- workspace layout ----
static constexpr size_t A8_OFF   = 0;
static constexpr size_t A8_BYTES = (size_t)BATCH * IN_CH;    // 32 MB
static constexpr size_t BT_OFF   = A8_OFF + A8_BYTES;
static constexpr size_t BT_BYTES = (size_t)NUNITS * IN_CH;   // 16 MB
static constexpr int    NPART    = 4096;
static constexpr size_t PART_OFF = BT_OFF + BT_BYTES;
static constexpr size_t SCALE_OFF= PART_OFF + NPART * sizeof(float);

// ------------------------------------------------------------- scale finalize
__global__ __launch_bounds__(TPB) void k_scale(const float* __restrict__ partials,
                                               float* __restrict__ scale) {
    __shared__ float red[TPB];
    float s = 0.f;
    for (int i = threadIdx.x; i < NPART; i += TPB) s += partials[i];
    red[threadIdx.x] = s;
    __syncthreads();
    for (int off = TPB / 2; off > 0; off >>= 1) {
        if ((int)threadIdx.x < off) red[threadIdx.x] += red[threadIdx.x + off];
        __syncthreads();
    }
    if (threadIdx.x == 0) {
        float E = red[0] / (float)((size_t)IN_CH * NUNITS);
        *scale = E / 7.0f;
    }
}

// ------------------------------------------------------------- quantize A
__device__ __forceinline__ unsigned int q4(float4 v) {
    unsigned int b0 = (unsigned int)(int)rintf(fminf(1.0f, fabsf(v.x)) * 7.0f);
    unsigned int b1 = (unsigned int)(int)rintf(fminf(1.0f, fabsf(v.y)) * 7.0f);
    unsigned int b2 = (unsigned int)(int)rintf(fminf(1.0f, fabsf(v.z)) * 7.0f);
    unsigned int b3 = (unsigned int)(int)rintf(fminf(1.0f, fabsf(v.w)) * 7.0f);
    return b0 | (b1 << 8) | (b2 << 16) | (b3 << 24);
}

__global__ __launch_bounds__(TPB) void k_quant_a(const float4* __restrict__ x4,
                                                 uint4* __restrict__ a16) {
    const size_t t = (size_t)blockIdx.x * TPB + threadIdx.x;
    uint4 o;
    o.x = q4(x4[t * 4 + 0]);
    o.y = q4(x4[t * 4 + 1]);
    o.z = q4(x4[t * 4 + 2]);
    o.w = q4(x4[t * 4 + 3]);
    a16[t] = o;
}

// -------------------------- sign(W) transpose to [N][K]  +  fused |W| partial sum
__global__ __launch_bounds__(TPB) void k_signT(const float* __restrict__ W,
                                               char* __restrict__ bt,
                                               float* __restrict__ partials) {
    __shared__ char tile[64][68];
    __shared__ float red[TPB];
    const int bk = blockIdx.x & 63;
    const int bn = blockIdx.x >> 6;
    const int t  = threadIdx.x;
    const int c  = t & 63;
    const int r0 = t >> 6;
    float asum = 0.f;
#pragma unroll
    for (int i = 0; i < 16; ++i) {
        int r = i * 4 + r0;
        float w = W[(size_t)(bk * 64 + r) * NUNITS + bn * 64 + c];
        asum += fabsf(w);
        tile[c][r] = (w > 0.f) ? 1 : ((w < 0.f) ? -1 : 0);
    }
    __syncthreads();
    const int n  = t >> 2;
    const int kk = (t & 3) * 16;
    char o[16];
#pragma unroll
    for (int j = 0; j < 16; ++j) o[j] = tile[n][kk + j];
    *(uint4*)(bt + (size_t)(bn * 64 + n) * IN_CH + bk * 64 + kk) = *(const uint4*)o;

    red[t] = asum;
    __syncthreads();
    for (int off = TPB / 2; off > 0; off >>= 1) {
        if (t < off) red[t] += red[t + off];
        __syncthreads();
    }
    if (t == 0) partials[blockIdx.x] = red[0];
}

// ---------------------------------------------------------------- GEMM
// 256x256 block tile, BK=64, 8 waves (2Mx4N), mfma_i32_16x16x64_i8.
// LDS: 3 buffers x [256 rows][128B], row = A 64B || B 64B, slot ^= (row&7).
__device__ __forceinline__ void gload_lds16(const void* g, void* l) {
    __builtin_amdgcn_global_load_lds((const __attribute__((address_space(1))) void*)g,
                                     (__attribute__((address_space(3))) void*)l,
                                     16, 0, 0);
}

#define VMCNT4   asm volatile("s_waitcnt vmcnt(4)" ::: "memory")
#define VMCNT0   asm volatile("s_waitcnt vmcnt(0)" ::: "memory")
#define LGKM0    asm volatile("s_waitcnt lgkmcnt(0)" ::: "memory")
#define SCHEDB   __builtin_amdgcn_sched_barrier(0)
#define BARRIER  __builtin_amdgcn_s_barrier()
#define PRIO1    __builtin_amdgcn_s_setprio(1)
#define PRIO0    __builtin_amdgcn_s_setprio(0)

static constexpr int NT = IN_CH / 64;   // 64 K-tiles

__global__ __launch_bounds__(512, 2) void k_gemm(const char* __restrict__ A8,
                                                 const char* __restrict__ BT,
                                                 const float* __restrict__ scale_p,
                                                 const float* __restrict__ bias,
                                                 float* __restrict__ out) {
    __shared__ char Ms[3][32768];   // [row 0..255][128B = A 64B || B 64B], swizzled

    const int t    = threadIdx.x;
    const int bid  = blockIdx.x;                  // 512 blocks
    const int swzb = (bid & 7) * 64 + (bid >> 3); // XCD swizzle (bijective)
    const int bRow = swzb >> 4;                   // 0..31
    const int bCol = swzb & 15;                   // 0..15
    const int lane = t & 63;
    const int wid  = t >> 6;
    const int wm   = wid >> 2;                    // 0..1
    const int wn   = wid & 3;                     // 0..3
    const int lr   = lane & 15;
    const int lk4  = lane >> 4;                   // 0..3

    const size_t aBase = (size_t)(bRow * 256) * IN_CH;
    const size_t bBase = (size_t)(bCol * 256) * IN_CH;

    // frag read byte offsets within a 128B row (slot = logical ^ (row&7); row&7 == lr&7)
    const int aswz = ((lk4 ^ (lr & 7)) << 4);     // A logical slots 0..3
    const int bswz = aswz ^ 64;                   // B logical slots 4..7

    // stage addressing: thread t covers (row = h*64 + (t>>3), physical slot t&7)
    const int srow  = t >> 3;                     // 0..63 within an issue
    const int pslot = t & 7;
    const int lslot = pslot ^ (srow & 7);         // logical slot held at this dest
    const char* mbase = (lslot < 4) ? (A8 + aBase) : (BT + bBase);
    const char* sbase = mbase + (size_t)srow * IN_CH + (size_t)((lslot & 3) << 4);
    // per (kt,h): src = sbase + h*64*IN_CH + kt*64 ; dest = STG + h*8192 + wid*1024

    v4i acc[8][4] = {};

#define STAGE4(kt, STG)                                                         \
    _Pragma("unroll") for (int h = 0; h < 4; ++h)                               \
        gload_lds16(sbase + (size_t)h * 64 * IN_CH + (size_t)(kt) * 64,         \
                    (STG) + h * 8192 + wid * 1024)

#define TILE(kt, CUR, STG, LAST)                                                \
    do {                                                                        \
        SCHEDB; LGKM0;                                                         \
        if (LAST) { VMCNT0; } else { VMCNT4; }                                  \
        BARRIER; SCHEDB;                                                        \
        if ((kt) + 2 < NT) { STAGE4((kt) + 2, STG); }                           \
        v4i a_[8], b_[4];                                                       \
        _Pragma("unroll") for (int m = 0; m < 8; ++m)                           \
            a_[m] = *(const v4i*)((CUR) + (wm * 128 + m * 16 + lr) * 128 + aswz); \
        _Pragma("unroll") for (int n = 0; n < 4; ++n)                           \
            b_[n] = *(const v4i*)((CUR) + (wn * 64 + n * 16 + lr) * 128 + bswz); \
        PRIO1;                                                                  \
        _Pragma("unroll") for (int m = 0; m < 8; ++m)                           \
            _Pragma("unroll") for (int n = 0; n < 4; ++n)                       \
                acc[m][n] = __builtin_amdgcn_mfma_i32_16x16x64_i8(              \
                    a_[m], b_[n], acc[m][n], 0, 0, 0);                          \
        PRIO0;                                                                  \
    } while (0)

    char* B0 = (char*)Ms[0];
    char* B1 = (char*)Ms[1];
    char* B2 = (char*)Ms[2];

    // prologue: stage tiles 0 and 1 (8 issues outstanding)
    STAGE4(0, B0);
    STAGE4(1, B1);

    // tiles 0..62 (21 x 3, static buffer rotation), tail tile 63
    for (int T = 0; T < NT - 1; T += 3) {
        TILE(T,     B0, B2, false);
        TILE(T + 1, B1, B0, false);
        TILE(T + 2, B2, B1, false);
    }
    TILE(NT - 1, B0, B2, true);

    // ---- epilogue
    const float scale = *scale_p;
    const int orow0 = bRow * 256 + wm * 128;
    const int ocol0 = bCol * 256 + wn * 64;
#pragma unroll
    for (int m = 0; m < 8; ++m) {
#pragma unroll
        for (int n = 0; n < 4; ++n) {
            const int col = ocol0 + n * 16 + lr;
            const float bb = bias[col];
            const int rbase = orow0 + m * 16 + lk4 * 4;
#pragma unroll
            for (int j = 0; j < 4; ++j)
                out[(size_t)(rbase + j) * NUNITS + col] = scale * (float)acc[m][n][j] + bb;
        }
    }
#undef STAGE4
#undef TILE
}

// ---------------------------------------------------------------- launch
extern "C" void kernel_launch(void* const* d_in, const int* in_sizes, int n_in,
                              void* d_out, int out_size, void* d_ws, size_t ws_size,
                              hipStream_t stream) {
    const float* x  = (const float*)d_in[0];
    const float* W  = (const float*)d_in[1];
    const float* b  = (const float*)d_in[2];
    float* out      = (float*)d_out;

    char*  ws       = (char*)d_ws;
    char*  A8       = ws + A8_OFF;
    char*  BT       = ws + BT_OFF;
    float* partials = (float*)(ws + PART_OFF);
    float* scale    = (float*)(ws + SCALE_OFF);

    k_signT<<<(IN_CH / 64) * (NUNITS / 64), TPB, 0, stream>>>(W, BT, partials);
    k_scale<<<1, TPB, 0, stream>>>(partials, scale);
    k_quant_a<<<(BATCH * (IN_CH / 16)) / TPB, TPB, 0, stream>>>((const float4*)x, (uint4*)A8);
    k_gemm<<<(BATCH / 256) * (NUNITS / 256), 512, 0, stream>>>(A8, BT, scale, b, out);
}